// Round 1
// baseline (216.071 us; speedup 1.0000x reference)
//
#include <hip/hip_runtime.h>
#include <cstdint>

// Two-link planar arm forward dynamics: qdd = M(q)^-1 (tau - h(q,dq)).
// fp32 in / fp32 out. Purely elementwise -> memory/latency-bound.
//
// Round-5 result: nontemporal loads+stores, 50.7 us/dispatch, 3.3 TB/s HBM,
// 8.6 B/cyc/CU effective vs 10.2 ceiling (m13 copy). FETCH_SIZE 98 MB of a
// 192 MB input set => half the reads already hit L3 across dispatches.
//
// Round-6 theory: limiter = per-CU outstanding-miss cap x avg latency.
// nt loads mark lines evict-first in L2/L3 (bad: inputs are re-read every
// dispatch; only outputs are re-poisoned). Want L1-bypass (avoid the L1
// miss-tracking throttle that cost round 4 87us) but TEMPORAL L2/L3
// allocation -> more L3 hits -> lower avg latency -> more B/cyc at the
// same miss cap. No builtin for that combo, so: inline-asm
// global_load_dwordx4 with sc0 only (no nt), explicit vmcnt(0) +
// sched_barrier fence before consumers. Stores remain nontemporal
// (write-once; allocation would evict inputs from L3).
// Predict: FETCH_SIZE 98 -> ~50-70 MB, dur 50.7 -> ~42-45 us/dispatch.

#define BLOCK 256
#define GRID  2048   // 8 blocks/CU * 256 CU -> full 32 waves/CU occupancy

typedef float f4 __attribute__((ext_vector_type(4)));

// L1-bypassing, L2/L3-temporal 16B load (sc0, no nt).
__device__ __forceinline__ f4 ld_sc0(const f4* p) {
    f4 r;
    asm volatile("global_load_dwordx4 %0, %1, off sc0"
                 : "=v"(r)
                 : "v"(p));
    return r;
}

__device__ __forceinline__ f4 fd_compute(f4 qv, f4 dv, f4 tv) {
    // Arm constants (L1=L2=1, C1=C2=0.5, M1=M2=1, I1=I2=0.1, G=9.81)
    const float alpha = 1.7f;     // I1 + M1*C1^2 + I2 + M2*(L1^2 + C2^2)
    const float beta  = 0.5f;     // M2*L1*C2
    const float delta = 0.35f;    // I2 + M2*C2^2  (== M22)
    const float G     = 9.81f;
    const float gA    = 1.5f * G; // (M1*C1 + M2*L1)*G
    const float gB    = 0.5f * G; // M2*C2*G

    f4 ov;

#pragma unroll
    for (int j = 0; j < 2; ++j) {
        float q1   = qv[2 * j + 0];
        float q2   = qv[2 * j + 1];
        float dq1  = dv[2 * j + 0];
        float dq2  = dv[2 * j + 1];
        float tau1 = tv[2 * j + 0];
        float tau2 = tv[2 * j + 1];

        float c2 = __cosf(q2);
        float s2 = __sinf(q2);

        float M11 = alpha + 2.0f * beta * c2;
        float M12 = delta + beta * c2;
        float M22 = delta;

        float cq1  = __cosf(q1);
        float cq12 = __cosf(q1 + q2);

        float g1 = gA * cq1 + gB * cq12;
        float g2 = gB * cq12;

        float h1 = -beta * s2 * (2.0f * dq1 * dq2 + dq2 * dq2) + g1;
        float h2 =  beta * s2 * dq1 * dq1 + g2;

        float r1 = tau1 - h1;
        float r2 = tau2 - h2;

        float det  = M11 * M22 - M12 * M12;
        float rdet = __builtin_amdgcn_rcpf(det);   // v_rcp_f32, ~1 ulp

        ov[2 * j + 0] = (M22 * r1 - M12 * r2) * rdet;
        ov[2 * j + 1] = (M11 * r2 - M12 * r1) * rdet;
    }
    return ov;
}

__global__ __launch_bounds__(BLOCK) void fd_qdd_kernel(
    const f4* __restrict__ qp,
    const f4* __restrict__ dqp,
    const f4* __restrict__ taup,
    f4* __restrict__ outp,
    int nvec)  // number of float4 groups (= 2 rows each)
{
    const int tid = blockIdx.x * BLOCK + threadIdx.x;
    const int nt  = GRID * BLOCK;          // total threads (grid-stride)
    const int nt2 = 2 * nt;

    // Main loop: 2 iterations pipelined — all 6 sc0 loads issued
    // before either compute. Explicit vmcnt fence (asm loads are invisible
    // to the compiler's waitcnt bookkeeping); sched_barrier keeps the
    // consumers from being hoisted above the fence (rule #18).
    int idx = tid;
    for (; idx + nt < nvec; idx += nt2) {
        int i0 = idx, i1 = idx + nt;
        f4 q0 = ld_sc0(&qp[i0]);
        f4 d0 = ld_sc0(&dqp[i0]);
        f4 t0 = ld_sc0(&taup[i0]);
        f4 q1 = ld_sc0(&qp[i1]);
        f4 d1 = ld_sc0(&dqp[i1]);
        f4 t1 = ld_sc0(&taup[i1]);

        asm volatile("s_waitcnt vmcnt(0)");
        __builtin_amdgcn_sched_barrier(0);

        f4 o0 = fd_compute(q0, d0, t0);
        f4 o1 = fd_compute(q1, d1, t1);

        __builtin_nontemporal_store(o0, &outp[i0]);
        __builtin_nontemporal_store(o1, &outp[i1]);
    }
    // Tail (not taken for B = 8388608, but keep it general).
    if (idx < nvec) {
        f4 q = __builtin_nontemporal_load(&qp[idx]);
        f4 d = __builtin_nontemporal_load(&dqp[idx]);
        f4 t = __builtin_nontemporal_load(&taup[idx]);
        f4 o = fd_compute(q, d, t);
        __builtin_nontemporal_store(o, &outp[idx]);
    }
}

extern "C" void kernel_launch(void* const* d_in, const int* in_sizes, int n_in,
                              void* d_out, int out_size, void* d_ws, size_t ws_size,
                              hipStream_t stream) {
    const f4* q   = (const f4*)d_in[0];
    const f4* dq  = (const f4*)d_in[1];
    const f4* tau = (const f4*)d_in[2];
    f4*       out = (f4*)d_out;

    int n_elems = in_sizes[0];      // B*2 fp32 elements
    int nvec    = n_elems / 4;      // 4 fp32 per float4 (2 rows)

    fd_qdd_kernel<<<GRID, BLOCK, 0, stream>>>(q, dq, tau, out, nvec);
}

// Round 2
// 198.434 us; speedup vs baseline: 1.0889x; 1.0889x over previous
//
#include <hip/hip_runtime.h>
#include <cstdint>

// Two-link planar arm forward dynamics: qdd = M(q)^-1 (tau - h(q,dq)).
// fp32 in / fp32 out. Purely elementwise -> memory/latency-bound.
//
// Round-6 post-mortem: sc0 loads = plain loads (87 us, L1 miss-cap throttle
// returns). sc0 does NOT bypass L1 on gfx950. FETCH unchanged at 98 MB in
// both variants => nt loads never hurt L3 retention. nt is the right path.
//
// Round-7 theory: at round-5's 50.7 us we deliver 256 MB = 5.05 TB/s = 80%
// of copy ceiling; HBM itself only 3.3 TB/s (L3 absorbs half the reads);
// VALU 16%; MLP ample (192 KB in flight vs ~9 KB needed). The anomaly is
// OccupancyPercent ~51% despite VGPR=32/LDS=0: GRID=2048 is exactly 1.0x
// machine capacity, so the dispatch has no backlog and ends in a long
// occupancy-decay tail (~20% time-avg loss ~= the 20% gap to ceiling).
// Fix: 4x oversubscription (GRID 8192), per-thread work drops to one
// pipelined iteration; steady state identical, drain tail ~4x shorter.
// Predict: Occupancy 51->65-80%, dur 50.7 -> ~43-46 us, FETCH ~98 MB.

#define BLOCK 256
#define GRID  8192   // 32 blocks/CU queued; 4x oversubscription for tail smoothing

typedef float f4 __attribute__((ext_vector_type(4)));

__device__ __forceinline__ f4 fd_compute(f4 qv, f4 dv, f4 tv) {
    // Arm constants (L1=L2=1, C1=C2=0.5, M1=M2=1, I1=I2=0.1, G=9.81)
    const float alpha = 1.7f;     // I1 + M1*C1^2 + I2 + M2*(L1^2 + C2^2)
    const float beta  = 0.5f;     // M2*L1*C2
    const float delta = 0.35f;    // I2 + M2*C2^2  (== M22)
    const float G     = 9.81f;
    const float gA    = 1.5f * G; // (M1*C1 + M2*L1)*G
    const float gB    = 0.5f * G; // M2*C2*G

    f4 ov;

#pragma unroll
    for (int j = 0; j < 2; ++j) {
        float q1   = qv[2 * j + 0];
        float q2   = qv[2 * j + 1];
        float dq1  = dv[2 * j + 0];
        float dq2  = dv[2 * j + 1];
        float tau1 = tv[2 * j + 0];
        float tau2 = tv[2 * j + 1];

        float c2 = __cosf(q2);
        float s2 = __sinf(q2);

        float M11 = alpha + 2.0f * beta * c2;
        float M12 = delta + beta * c2;
        float M22 = delta;

        float cq1  = __cosf(q1);
        float cq12 = __cosf(q1 + q2);

        float g1 = gA * cq1 + gB * cq12;
        float g2 = gB * cq12;

        float h1 = -beta * s2 * (2.0f * dq1 * dq2 + dq2 * dq2) + g1;
        float h2 =  beta * s2 * dq1 * dq1 + g2;

        float r1 = tau1 - h1;
        float r2 = tau2 - h2;

        float det  = M11 * M22 - M12 * M12;
        float rdet = __builtin_amdgcn_rcpf(det);   // v_rcp_f32, ~1 ulp

        ov[2 * j + 0] = (M22 * r1 - M12 * r2) * rdet;
        ov[2 * j + 1] = (M11 * r2 - M12 * r1) * rdet;
    }
    return ov;
}

__global__ __launch_bounds__(BLOCK) void fd_qdd_kernel(
    const f4* __restrict__ qp,
    const f4* __restrict__ dqp,
    const f4* __restrict__ taup,
    f4* __restrict__ outp,
    int nvec)  // number of float4 groups (= 2 rows each)
{
    const int tid = blockIdx.x * BLOCK + threadIdx.x;
    const int nt  = GRID * BLOCK;          // total threads (grid-stride)
    const int nt2 = 2 * nt;

    // Main loop: 2 elements pipelined — all 6 nt loads issued before
    // either compute (compiler inserts fine-grained vmcnt waits).
    int idx = tid;
    for (; idx + nt < nvec; idx += nt2) {
        int i0 = idx, i1 = idx + nt;
        f4 q0 = __builtin_nontemporal_load(&qp[i0]);
        f4 d0 = __builtin_nontemporal_load(&dqp[i0]);
        f4 t0 = __builtin_nontemporal_load(&taup[i0]);
        f4 q1 = __builtin_nontemporal_load(&qp[i1]);
        f4 d1 = __builtin_nontemporal_load(&dqp[i1]);
        f4 t1 = __builtin_nontemporal_load(&taup[i1]);

        f4 o0 = fd_compute(q0, d0, t0);
        f4 o1 = fd_compute(q1, d1, t1);

        __builtin_nontemporal_store(o0, &outp[i0]);
        __builtin_nontemporal_store(o1, &outp[i1]);
    }
    // Tail: general-nvec correctness (steps by nt so the i1 half of a
    // partial pipelined pair is also covered).
    for (; idx < nvec; idx += nt) {
        f4 q = __builtin_nontemporal_load(&qp[idx]);
        f4 d = __builtin_nontemporal_load(&dqp[idx]);
        f4 t = __builtin_nontemporal_load(&taup[idx]);
        f4 o = fd_compute(q, d, t);
        __builtin_nontemporal_store(o, &outp[idx]);
    }
}

extern "C" void kernel_launch(void* const* d_in, const int* in_sizes, int n_in,
                              void* d_out, int out_size, void* d_ws, size_t ws_size,
                              hipStream_t stream) {
    const f4* q   = (const f4*)d_in[0];
    const f4* dq  = (const f4*)d_in[1];
    const f4* tau = (const f4*)d_in[2];
    f4*       out = (f4*)d_out;

    int n_elems = in_sizes[0];      // B*2 fp32 elements
    int nvec    = n_elems / 4;      // 4 fp32 per float4 (2 rows)

    fd_qdd_kernel<<<GRID, BLOCK, 0, stream>>>(q, dq, tau, out, nvec);
}